// Round 1
// baseline (116.142 us; speedup 1.0000x reference)
//
#include <hip/hip_runtime.h>

#define HC 256
#define WC 256
#define CC 96
#define BB 4
#define OH 258
#define OW 258
#define TOX 30
#define TOY 14
#define RX 32
#define RY 16

// out[b,d,y,x] = (1/864) * sum_{a,b2 in [0,3)} r(y+a-2, x+b2-2; tj,ti)
// r(h,w; tj,ti) = sum_c x1[b,c,h,w] * x2[b,c,h+tj,w+ti]   (OOB -> 0)
// d = (tj+1)*3 + (ti+1), tj,ti in {-1,0,1}

__global__ __launch_bounds__(256) void corr2d_kernel(
    const float* __restrict__ x1, const float* __restrict__ x2,
    float* __restrict__ out)
{
    const int tx = threadIdx.x;            // 0..31
    const int ty = threadIdx.y;            // 0..7
    const int bx = blockIdx.x, by = blockIdx.y, b = blockIdx.z;
    const int x0 = bx * TOX, y0 = by * TOY;

    // r-tile coordinates this thread owns (2 pixels, rows ty and ty+8)
    const int w  = x0 - 2 + tx;
    const int h0 = y0 - 2 + ty;
    const int h1 = h0 + 8;

    const size_t plane = (size_t)HC * WC;
    const float* p1 = x1 + (size_t)b * CC * plane;
    const float* p2 = x2 + (size_t)b * CC * plane;

    float acc[2][9];
#pragma unroll
    for (int i = 0; i < 2; ++i)
#pragma unroll
        for (int d = 0; d < 9; ++d) acc[i][d] = 0.f;

    // interior test: all x1 taps (rows h0..h1, col w) and x2 taps (+-1) in range
    const bool interior = (x0 >= 3) && (x0 + 30 <= WC - 1) &&
                          (y0 >= 3) && (y0 + 14 <= HC - 1);

    if (interior) {
        const float* q1 = p1 + (size_t)(h0 * WC + w);
        const float* q2 = p2 + (size_t)(h0 * WC + w);
        for (int c = 0; c < CC; ++c) {
            const float a0 = q1[0];
            const float a1 = q1[8 * WC];
#pragma unroll
            for (int tj = -1; tj <= 1; ++tj) {
#pragma unroll
                for (int ti = -1; ti <= 1; ++ti) {
                    const int d = (tj + 1) * 3 + (ti + 1);
                    acc[0][d] = fmaf(a0, q2[tj * WC + ti], acc[0][d]);
                    acc[1][d] = fmaf(a1, q2[(tj + 8) * WC + ti], acc[1][d]);
                }
            }
            q1 += plane; q2 += plane;
        }
    } else {
        // boundary path: clamped addresses + masks (computed once, loop-invariant)
        int rows[6]; bool rv[6];
        const int hh[6] = {h0 - 1, h0, h0 + 1, h1 - 1, h1, h1 + 1};
#pragma unroll
        for (int j = 0; j < 6; ++j) {
            rv[j] = ((unsigned)hh[j] < (unsigned)HC);
            int hcl = hh[j] < 0 ? 0 : (hh[j] > HC - 1 ? HC - 1 : hh[j]);
            rows[j] = hcl * WC;
        }
        int cols[3]; bool cv[3];
#pragma unroll
        for (int i = 0; i < 3; ++i) {
            int ww = w - 1 + i;
            cv[i] = ((unsigned)ww < (unsigned)WC);
            cols[i] = ww < 0 ? 0 : (ww > WC - 1 ? WC - 1 : ww);
        }
        const bool v0 = ((unsigned)h0 < (unsigned)HC) && ((unsigned)w < (unsigned)WC);
        const bool v1 = ((unsigned)h1 < (unsigned)HC) && ((unsigned)w < (unsigned)WC);
        const int wcl = w < 0 ? 0 : (w > WC - 1 ? WC - 1 : w);
        const int off1_0 = (h0 < 0 ? 0 : (h0 > HC - 1 ? HC - 1 : h0)) * WC + wcl;
        const int off1_1 = (h1 < 0 ? 0 : (h1 > HC - 1 ? HC - 1 : h1)) * WC + wcl;

        const float* q1 = p1;
        const float* q2 = p2;
        for (int c = 0; c < CC; ++c) {
            const float a0 = v0 ? q1[off1_0] : 0.f;
            const float a1 = v1 ? q1[off1_1] : 0.f;
#pragma unroll
            for (int jr = 0; jr < 3; ++jr) {
#pragma unroll
                for (int i = 0; i < 3; ++i) {
                    const int d = jr * 3 + i;
                    const float u0 = (rv[jr] && cv[i])     ? q2[rows[jr] + cols[i]]     : 0.f;
                    const float u1 = (rv[jr + 3] && cv[i]) ? q2[rows[jr + 3] + cols[i]] : 0.f;
                    acc[0][d] = fmaf(a0, u0, acc[0][d]);
                    acc[1][d] = fmaf(a1, u1, acc[1][d]);
                }
            }
            q1 += plane; q2 += plane;
        }
    }

    // stage r into LDS: 9 planes of RY x RX
    __shared__ float rl[9][RY][RX];
#pragma unroll
    for (int d = 0; d < 9; ++d) {
        rl[d][ty][tx]     = acc[0][d];
        rl[d][ty + 8][tx] = acc[1][d];
    }
    __syncthreads();

    // 3x3 box-sum -> output tile TOY x TOX
    const int tid = ty * 32 + tx;
    for (int j = tid; j < TOX * TOY; j += 256) {
        const int oy = j / TOX, ox = j - oy * TOX;
        const int y = y0 + oy, x = x0 + ox;
        if (y < OH && x < OW) {
#pragma unroll
            for (int d = 0; d < 9; ++d) {
                float s = 0.f;
#pragma unroll
                for (int a = 0; a < 3; ++a)
#pragma unroll
                    for (int b2 = 0; b2 < 3; ++b2)
                        s += rl[d][oy + a][ox + b2];
                out[(((size_t)b * 9 + d) * OH + y) * OW + x] = s * (1.0f / 864.0f);
            }
        }
    }
}

extern "C" void kernel_launch(void* const* d_in, const int* in_sizes, int n_in,
                              void* d_out, int out_size, void* d_ws, size_t ws_size,
                              hipStream_t stream) {
    const float* x1 = (const float*)d_in[0];
    const float* x2 = (const float*)d_in[1];
    float* out = (float*)d_out;
    dim3 grid((OW + TOX - 1) / TOX, (OH + TOY - 1) / TOY, BB);
    dim3 block(32, 8);
    hipLaunchKernelGGL(corr2d_kernel, grid, block, 0, stream, x1, x2, out);
}

// Round 3
// 89.917 us; speedup vs baseline: 1.2917x; 1.2917x over previous
//
#include <hip/hip_runtime.h>

#define HC 256
#define WC 256
#define CC 96
#define BB 4
#define OH 258
#define OW 258
#define PLANE 65536          // HC*WC
#define TOX 56               // out cols per tile (must be mult of 4, <= 59)
#define TOY 6                // out rows per tile
#define RXC 64               // r-tile cols (16 quads)
#define RYC 8                // r-tile rows
#define NTX 5                // ceil(258/56)
#define NTY 43               // 258/6
#define CG 48                // channels per group (2 groups per block)

// out[b,d(tj,ti),y,x] = (1/864) * sum_{a,b2 in [0,3)} r(y-2+a, x-2+b2; tj,ti)
// r(h,w; tj,ti) = sum_c x1[b,c,h,w] * x2[b,c,h+tj-1,w+ti-1]  (OOB -> 0; d = tj*3+ti)

__device__ __forceinline__ float4 ld4(const float* p) {
    return *reinterpret_cast<const float4*>(p);
}

// a = x1 quad; window W[0..5] = x2 cols w-1..w+4 of row h+tj-1.
// px i (i=0..3) with shift ti uses W[i+ti].
#define FMA3(d0, L, R, e)                                                                  \
    do {                                                                                   \
        const float W0 = (L).w, W1 = (R).x, W2 = (R).y, W3 = (R).z, W4 = (R).w, W5 = (e);  \
        acc[d0].x = fmaf(a.x, W0, acc[d0].x);                                              \
        acc[d0].y = fmaf(a.y, W1, acc[d0].y);                                              \
        acc[d0].z = fmaf(a.z, W2, acc[d0].z);                                              \
        acc[d0].w = fmaf(a.w, W3, acc[d0].w);                                              \
        acc[d0+1].x = fmaf(a.x, W1, acc[d0+1].x);                                          \
        acc[d0+1].y = fmaf(a.y, W2, acc[d0+1].y);                                          \
        acc[d0+1].z = fmaf(a.z, W3, acc[d0+1].z);                                          \
        acc[d0+1].w = fmaf(a.w, W4, acc[d0+1].w);                                          \
        acc[d0+2].x = fmaf(a.x, W2, acc[d0+2].x);                                          \
        acc[d0+2].y = fmaf(a.y, W3, acc[d0+2].y);                                          \
        acc[d0+2].z = fmaf(a.z, W4, acc[d0+2].z);                                          \
        acc[d0+2].w = fmaf(a.w, W5, acc[d0+2].w);                                          \
    } while (0)

__global__ __launch_bounds__(256) void corr2d_kernel(
    const float* __restrict__ x1, const float* __restrict__ x2,
    float* __restrict__ out)
{
    const int tid = threadIdx.x;
    const int tx  = tid & 15;        // quad-column index (cols 4*tx .. 4*tx+3 of r-tile)
    const int rg  = tid >> 4;        // 0..15
    const int row = rg & 7;          // r-row within tile
    const int g   = rg >> 3;         // channel group 0/1

    const int bx = blockIdx.x, by = blockIdx.y, b = blockIdx.z;
    const int rs  = TOX * bx - 4;    // r-tile col start (global; == 0 mod 4)
    const int rsy = TOY * by - 2;    // r-tile row start
    const int w = rs + 4 * tx;       // this thread's quad start col (== 0 mod 4)
    const int h = rsy + row;         // this thread's r row

    const float* x1b = x1 + (size_t)(b * CC + g * CG) * PLANE;
    const float* x2b = x2 + (size_t)(b * CC + g * CG) * PLANE;

    float4 acc[9];
#pragma unroll
    for (int d = 0; d < 9; ++d) acc[d] = make_float4(0.f, 0.f, 0.f, 0.f);

    const int lp1 = (tid & 63) + 1;  // shfl source lane (tx+1 same row; wrap garbage unused)

    const bool interior = (bx >= 1) && (bx <= 3) && (by >= 1) && (by <= 41);

    if (interior) {
        const float* q1 = x1b + h * WC + w;
        const float* q2 = x2b + h * WC + (w - 4);
#pragma unroll 2
        for (int c = 0; c < CG; ++c) {
            const float4 a  = ld4(q1);
            const float4 L0 = ld4(q2 - WC), R0 = ld4(q2 - WC + 4);
            const float4 L1 = ld4(q2),      R1 = ld4(q2 + 4);
            const float4 L2 = ld4(q2 + WC), R2 = ld4(q2 + WC + 4);
            const float e0 = __shfl(R0.x, lp1);
            const float e1 = __shfl(R1.x, lp1);
            const float e2 = __shfl(R2.x, lp1);
            FMA3(0, L0, R0, e0);
            FMA3(3, L1, R1, e1);
            FMA3(6, L2, R2, e2);
            q1 += PLANE; q2 += PLANE;
        }
    } else {
        // channel-invariant clamped offsets + full-vector validity masks.
        // All loads are 4-aligned and 4-wide, so each is fully in-image or fully out.
        bool hv[3]; int hro[3];
#pragma unroll
        for (int t = 0; t < 3; ++t) {
            const int hr = h - 1 + t;
            hv[t] = ((unsigned)hr < (unsigned)HC);
            const int hc = hr < 0 ? 0 : (hr > HC - 1 ? HC - 1 : hr);
            hro[t] = hc * WC;
        }
        const int wl = w - 4;
        const bool cvL = ((unsigned)wl <= (unsigned)(WC - 4));
        const bool cvR = ((unsigned)w  <= (unsigned)(WC - 4));
        const int  cL = wl < 0 ? 0 : (wl > WC - 4 ? WC - 4 : wl);
        const int  cR = w  < 0 ? 0 : (w  > WC - 4 ? WC - 4 : w);
        const bool mA = hv[1] && cvR;
        const int  offA = hro[1] + cR;

        const float* q1 = x1b;
        const float* q2 = x2b;
        for (int c = 0; c < CG; ++c) {
            float4 a = ld4(q1 + offA);
            if (!mA) a = make_float4(0.f, 0.f, 0.f, 0.f);
            float4 Ls[3], Rs[3];
#pragma unroll
            for (int t = 0; t < 3; ++t) {
                float4 L = ld4(q2 + hro[t] + cL);
                float4 R = ld4(q2 + hro[t] + cR);
                if (!(hv[t] && cvL)) L = make_float4(0.f, 0.f, 0.f, 0.f);
                if (!(hv[t] && cvR)) R = make_float4(0.f, 0.f, 0.f, 0.f);
                Ls[t] = L; Rs[t] = R;
            }
            const float e0 = __shfl(Rs[0].x, lp1);
            const float e1 = __shfl(Rs[1].x, lp1);
            const float e2 = __shfl(Rs[2].x, lp1);
            FMA3(0, Ls[0], Rs[0], e0);
            FMA3(3, Ls[1], Rs[1], e1);
            FMA3(6, Ls[2], Rs[2], e2);
            q1 += PLANE; q2 += PLANE;
        }
    }

    // combine the two channel-group partials in LDS
    __shared__ __align__(16) float rl[9][RYC][RXC];   // 18 KB
    if (g == 1) {
#pragma unroll
        for (int d = 0; d < 9; ++d)
            *reinterpret_cast<float4*>(&rl[d][row][4 * tx]) = acc[d];
    }
    __syncthreads();
    if (g == 0) {
#pragma unroll
        for (int d = 0; d < 9; ++d) {
            float4 v = *reinterpret_cast<float4*>(&rl[d][row][4 * tx]);
            v.x += acc[d].x; v.y += acc[d].y; v.z += acc[d].z; v.w += acc[d].w;
            *reinterpret_cast<float4*>(&rl[d][row][4 * tx]) = v;
        }
    }
    __syncthreads();

    // 3x3 box over r (window rows y-2..y, cols x-2..x) -> out tile
    const int x0 = TOX * bx, y0 = TOY * by;
    for (int j = tid; j < 9 * TOY * TOX; j += 256) {
        const int d  = j / (TOY * TOX);
        const int r2 = j - d * (TOY * TOX);
        const int oy = r2 / TOX;
        const int ox = r2 - oy * TOX;
        const int x = x0 + ox;
        if (x < OW) {
            float s = 0.f;
#pragma unroll
            for (int a2 = 0; a2 < 3; ++a2)
#pragma unroll
                for (int b2 = 0; b2 < 3; ++b2)
                    s += rl[d][oy + a2][ox + 2 + b2];
            out[((size_t)(b * 9 + d) * OH + (y0 + oy)) * OW + x] = s * (1.0f / 864.0f);
        }
    }
}

extern "C" void kernel_launch(void* const* d_in, const int* in_sizes, int n_in,
                              void* d_out, int out_size, void* d_ws, size_t ws_size,
                              hipStream_t stream) {
    const float* x1 = (const float*)d_in[0];
    const float* x2 = (const float*)d_in[1];
    float* out = (float*)d_out;
    dim3 grid(NTX, NTY, BB);
    dim3 block(256);
    hipLaunchKernelGGL(corr2d_kernel, grid, block, 0, stream, x1, x2, out);
}